// Round 7
// baseline (204.120 us; speedup 1.0000x reference)
//
#include <hip/hip_runtime.h>

namespace {
constexpr int L_ = 512;
constexpr int B_ = 1024;
constexpr int K_ = 64;
constexpr int START_I = 62;
constexpr int STOP_I = 63;
}

__device__ __forceinline__ float bcast0(float x) {
    return __int_as_float(__builtin_amdgcn_readfirstlane(__float_as_int(x)));
}

// DPP row-rotate of a float (ctl = 0x120 + r  ->  row_ror:r, 16-lane rows).
#define DPPF(x, ctl)                                                        \
    __int_as_float(__builtin_amdgcn_update_dpp(                             \
        0, __float_as_int(x), (ctl), 0xF, 0xF, false))

// 16 fmacs for one block-copy c with E-bank Ea (r = 0..15 row rotations).
// DPP folds into v_fmac_f32 src0 (GCNDPPCombine); no SGPR traffic at all.
#define FROW(acc, c, Ea)                                                    \
    acc = fmaf((c),           Ea##_0,  acc);                                \
    acc = fmaf(DPPF(c,0x121), Ea##_1,  acc);                                \
    acc = fmaf(DPPF(c,0x122), Ea##_2,  acc);                                \
    acc = fmaf(DPPF(c,0x123), Ea##_3,  acc);                                \
    acc = fmaf(DPPF(c,0x124), Ea##_4,  acc);                                \
    acc = fmaf(DPPF(c,0x125), Ea##_5,  acc);                                \
    acc = fmaf(DPPF(c,0x126), Ea##_6,  acc);                                \
    acc = fmaf(DPPF(c,0x127), Ea##_7,  acc);                                \
    acc = fmaf(DPPF(c,0x128), Ea##_8,  acc);                                \
    acc = fmaf(DPPF(c,0x129), Ea##_9,  acc);                                \
    acc = fmaf(DPPF(c,0x12A), Ea##_10, acc);                                \
    acc = fmaf(DPPF(c,0x12B), Ea##_11, acc);                                \
    acc = fmaf(DPPF(c,0x12C), Ea##_12, acc);                                \
    acc = fmaf(DPPF(c,0x12D), Ea##_13, acc);                                \
    acc = fmaf(DPPF(c,0x12E), Ea##_14, acc);                                \
    acc = fmaf(DPPF(c,0x12F), Ea##_15, acc);

// One forward-recursion step, linear domain:
// p'_i = (sum_j E[i][j] p_j) * exp(emit_i).
// Broadcast-free matvec: 3 ds_bpermute block-shift copies (16/32/48 lanes)
// + row_ror DPP folded into the fmacs. EREG = emit loaded 4 steps ago.
#define CRF_STEP(EREG, TNEXT, RECEN)                                        \
    do {                                                                    \
        float ee = exp2f(EREG * 1.4426950408889634f);                       \
        {                                                                   \
            int tp = (TNEXT) < len ? (TNEXT) : (len - 1);                   \
            EREG = eb[(long)tp * (B_ * K_)];                                \
        }                                                                   \
        int pi_ = __float_as_int(p);                                        \
        float c1 = __int_as_float(__builtin_amdgcn_ds_bpermute(A16, pi_));  \
        float c2 = __int_as_float(__builtin_amdgcn_ds_bpermute(A32, pi_));  \
        float c3 = __int_as_float(__builtin_amdgcn_ds_bpermute(A48, pi_));  \
        float a0 = 0.f, a1 = 0.f, a2 = 0.f, a3 = 0.f;                       \
        FROW(a0, p,  Er0)                                                   \
        FROW(a1, c1, Er1)                                                   \
        FROW(a2, c2, Er2)                                                   \
        FROW(a3, c3, Er3)                                                   \
        float pn = ((a0 + a1) + (a2 + a3)) * ee;                            \
        if (RECEN) {                                                        \
            float p0 = bcast0(pn);                                          \
            int kk = (int)(__float_as_uint(p0) >> 23) - 127;                \
            pn *= __uint_as_float((unsigned)(127 - kk) << 23);              \
            base2 += (float)kk;                                             \
        }                                                                   \
        p = pn;                                                             \
    } while (0)

__global__ __launch_bounds__(64)
__attribute__((amdgpu_waves_per_eu(1, 1)))
void crf_kernel(
    const float* __restrict__ emit,    // (L,B,K)
    const float* __restrict__ trans,   // (K,K)
    const int* __restrict__ labels,    // (L,B)
    const float* __restrict__ masks,   // (L,B)
    float* __restrict__ out)           // (B,)
{
    const int lane = threadIdx.x & 63;
    const int b = blockIdx.x;
    constexpr float LOG2E = 1.4426950408889634f;
    constexpr float LN2 = 0.6931471805599453f;

    // Probe DPP row_ror:1 direction (receive-from-(i-1) vs (i+1)) so the
    // E-permutation below matches hardware semantics unconditionally.
    int w = __builtin_amdgcn_update_dpp(0, lane, 0x121, 0xF, 0xF, false);
    int sgn = (__builtin_amdgcn_readfirstlane(w) == 15) ? -1 : 1;

    // bpermute pull addresses for block shifts of 16/32/48 lanes.
    const int A16 = ((lane + 16) & 63) * 4;
    const int A32 = ((lane + 32) & 63) * 4;
    const int A48 = ((lane + 48) & 63) * 4;

    // E bank (a,r), lane i:  Er{a}_{r} = exp(T[i][jfun]),
    // jfun = ((i&48) + ((i + sgn*r)&15) + 16a) & 63 — so that after the
    // block-shift copy (a) and row_ror:r DPP, operand pairs line up.
#define MKER(a, r)                                                          \
    float Er##a##_##r = exp2f(                                              \
        trans[lane * K_ +                                                   \
              (((lane & 48) + ((lane + sgn * (r)) & 15) + 16 * (a)) & 63)]  \
        * LOG2E);                                                           \
    asm("" : "+v"(Er##a##_##r));
#define MKERA(a)                                                            \
    MKER(a, 0)  MKER(a, 1)  MKER(a, 2)  MKER(a, 3)                          \
    MKER(a, 4)  MKER(a, 5)  MKER(a, 6)  MKER(a, 7)                          \
    MKER(a, 8)  MKER(a, 9)  MKER(a, 10) MKER(a, 11)                         \
    MKER(a, 12) MKER(a, 13) MKER(a, 14) MKER(a, 15)
    MKERA(0) MKERA(1) MKERA(2) MKERA(3)
#undef MKERA
#undef MKER

    // len[b] = sum_t masks[t,b]  (masks are prefix masks)
    int len = 0;
    #pragma unroll
    for (int c = 0; c < L_ / 64; ++c)
        len += (int)masks[(c * 64 + lane) * B_ + b];
    #pragma unroll
    for (int off = 32; off >= 1; off >>= 1)
        len += __shfl_xor(len, off);

    // Linear-domain state: score_i = (log2 p_i + base2)*ln2.
    float p = (lane == START_I) ? 1.0f : 0.0f;
    float base2 = 0.0f;
    const float* eb = emit + b * K_ + lane;

    // 4-deep emit prefetch ring (len >= 128 always; 4-deep proven in R5/R6).
    float e0 = eb[0L * (B_ * K_)];
    float e1 = eb[1L * (B_ * K_)];
    float e2 = eb[2L * (B_ * K_)];
    float e3 = eb[3L * (B_ * K_)];

    int t = 0;
    for (; t + 4 <= len; t += 4) {
        CRF_STEP(e0, t + 4, 0);
        CRF_STEP(e1, t + 5, 0);
        CRF_STEP(e2, t + 6, 0);
        CRF_STEP(e3, t + 7, 1);
    }
    if (t < len) { CRF_STEP(e0, len - 1, 1); ++t; }
    if (t < len) { CRF_STEP(e1, len - 1, 1); ++t; }
    if (t < len) { CRF_STEP(e2, len - 1, 1); ++t; }

    // partition = LSE_k(score_k + T[STOP,k])
    float v = fmaf(__log2f(p) + base2, LN2, trans[STOP_I * K_ + lane]);
    float M = v;
    #pragma unroll
    for (int off = 32; off >= 1; off >>= 1)
        M = fmaxf(M, __shfl_xor(M, off));
    float pe = exp2f((v - M) * LOG2E);
    #pragma unroll
    for (int off = 32; off >= 1; off >>= 1)
        pe += __shfl_xor(pe, off);
    float part = fmaf(__log2f(pe), LN2, M);

    // gold score: lanes cover t = c*64 + lane
    float g = 0.0f;
    #pragma unroll
    for (int c = 0; c < L_ / 64; ++c) {
        int tt = c * 64 + lane;
        if (tt < len) {
            int lt = labels[tt * B_ + b];
            int lp;
            if (tt == 0) lp = START_I;
            else lp = labels[(tt - 1) * B_ + b];
            g += trans[lt * K_ + lp] + emit[((long)tt * B_ + b) * K_ + lt];
        }
    }
    #pragma unroll
    for (int off = 32; off >= 1; off >>= 1)
        g += __shfl_xor(g, off);
    int lastl = labels[(len - 1) * B_ + b];
    g += trans[STOP_I * K_ + lastl];

    if (lane == 0) out[b] = part - g;
}

extern "C" void kernel_launch(void* const* d_in, const int* in_sizes, int n_in,
                              void* d_out, int out_size, void* d_ws, size_t ws_size,
                              hipStream_t stream) {
    const float* emit = (const float*)d_in[0];
    const float* trans = (const float*)d_in[1];
    const int* labels = (const int*)d_in[2];
    const float* masks = (const float*)d_in[3];
    float* out = (float*)d_out;
    crf_kernel<<<B_, 64, 0, stream>>>(emit, trans, labels, masks, out);
}